// Round 1
// baseline (1687.512 us; speedup 1.0000x reference)
//
#include <hip/hip_runtime.h>
#include <math.h>

// ---------------- problem constants ----------------
#define BB 4
#define SS 2048
#define DD 2048
#define HH 16
#define NOPE 128
#define ROPE 64
#define VD 128
#define QKD 192         // NOPE+ROPE
#define KVR 512
#define NPAD 640        // KVR+ROPE padded to 128 multiple
#define ROWS (BB*SS)    // 8192

typedef __attribute__((ext_vector_type(8))) short bf16x8;
typedef __attribute__((ext_vector_type(4))) float f32x4;
typedef unsigned short bfu;
typedef __attribute__((address_space(1))) const void GV;
typedef __attribute__((address_space(3))) void LV;

__device__ __forceinline__ float bf2f(unsigned int u) {
    unsigned int i = u << 16; float f; __builtin_memcpy(&f, &i, 4); return f;
}
__device__ __forceinline__ unsigned int f2bf(float f) {
    unsigned int i; __builtin_memcpy(&i, &f, 4);
    return (i + 0x7fffu + ((i >> 16) & 1u)) >> 16;
}

// ---------------- cast fp32 -> bf16 (with optional zero pad) ----------------
__global__ void cast_f32_bf16(const float* __restrict__ src, bfu* __restrict__ dst,
                              long n_src, long n_dst) {
    long i = (long)blockIdx.x * blockDim.x + threadIdx.x;   // one float4 each
    if (i * 4 >= n_dst) return;
    unsigned int lo = 0, hi = 0;
    if (i * 4 < n_src) {
        float4 v = ((const float4*)src)[i];
        lo = f2bf(v.x) | (f2bf(v.y) << 16);
        hi = f2bf(v.z) | (f2bf(v.w) << 16);
    }
    ((uint2*)dst)[i] = make_uint2(lo, hi);
}

// ---------------- 128x128 tile bf16 GEMM, C = A[M,K] @ Bt[N,K]^T ----------------
// m97 structure: global_load_lds w=16 staging, 2 barriers/K-step, BK=64,
// row-XOR LDS swizzle (both-sides: pre-swizzled global source + swizzled ds_read).
template <int OUTF32>
__global__ void __launch_bounds__(256)
gemm_bt(const bfu* __restrict__ A, const bfu* __restrict__ Bt,
        void* __restrict__ Cv, int N, int K) {
    __shared__ __align__(16) char lds[32768];
    char* AsB = lds;
    char* BsB = lds + 16384;
    const int tid  = threadIdx.x;
    const int lane = tid & 63;
    const int wid  = tid >> 6;
    const int wr   = wid >> 1, wc = wid & 1;
    const long m0 = (long)blockIdx.y * 128;
    const long n0 = (long)blockIdx.x * 128;

    f32x4 acc[4][4] = {};

    const int lr = lane >> 3;            // row within 8-row stripe
    const int SB = (lane & 7) << 4;      // 16B slot within 128B row

    for (int k0 = 0; k0 < K; k0 += 64) {
        __syncthreads();                 // prior reads done before overwrite
#pragma unroll
        for (int i = 0; i < 4; ++i) {
            int rb = wid * 32 + i * 8;   // wave-uniform row base
            int R  = rb + lr;
            int c  = (SB ^ ((R & 7) << 4)) >> 1;   // pre-swizzled source column
            const bfu* gA = A  + (m0 + R) * (long)K + k0 + c;
            const bfu* gB = Bt + (n0 + R) * (long)K + k0 + c;
            __builtin_amdgcn_global_load_lds((GV*)gA, (LV*)(AsB + rb * 128), 16, 0, 0);
            __builtin_amdgcn_global_load_lds((GV*)gB, (LV*)(BsB + rb * 128), 16, 0, 0);
        }
        __syncthreads();                 // staged data visible
#pragma unroll
        for (int kk = 0; kk < 2; ++kk) {
            bf16x8 av[4], bv[4];
            const int cb = kk * 64 + ((lane >> 4) << 4);
#pragma unroll
            for (int m = 0; m < 4; ++m) {
                int R = wr * 64 + m * 16 + (lane & 15);
                av[m] = *(const bf16x8*)(AsB + R * 128 + (cb ^ ((R & 7) << 4)));
            }
#pragma unroll
            for (int n = 0; n < 4; ++n) {
                int R = wc * 64 + n * 16 + (lane & 15);
                bv[n] = *(const bf16x8*)(BsB + R * 128 + (cb ^ ((R & 7) << 4)));
            }
#pragma unroll
            for (int m = 0; m < 4; ++m)
#pragma unroll
                for (int n = 0; n < 4; ++n)
                    acc[m][n] = __builtin_amdgcn_mfma_f32_16x16x32_bf16(av[m], bv[n], acc[m][n], 0, 0, 0);
        }
    }

    const int cr = (lane >> 4) << 2;
    const int cc = lane & 15;
#pragma unroll
    for (int m = 0; m < 4; ++m)
#pragma unroll
        for (int n = 0; n < 4; ++n)
#pragma unroll
            for (int r = 0; r < 4; ++r) {
                long row = m0 + wr * 64 + m * 16 + cr + r;
                long col = n0 + wc * 64 + n * 16 + cc;
                if (OUTF32) ((float*)Cv)[row * N + col] = acc[m][n][r];
                else        ((bfu*)Cv)[row * N + col] = (bfu)f2bf(acc[m][n][r]);
            }
}

// ---------------- RoPE on q_pe + rearrange q -> [b][h][s][192] ----------------
__global__ void rope_q(const bfu* __restrict__ q1, bfu* __restrict__ qr,
                       const float* __restrict__ fc, const float* __restrict__ fs) {
    long t = (long)blockIdx.x * 256 + threadIdx.x;   // one (e,o) pair
    const long total = (long)BB * HH * SS * 96;
    if (t >= total) return;
    int  p  = (int)(t % 96);
    long r  = t / 96;
    int  h  = (int)(r % HH);
    long bs = r / HH;                 // b*S + s
    int  s  = (int)(bs % SS);
    long b_ = bs / SS;
    unsigned int v = *(const unsigned int*)(q1 + bs * (HH * QKD) + h * QKD + 2 * p);
    float e = bf2f(v & 0xffff), o = bf2f(v >> 16);
    if (p >= 64) {
        int i = p - 64;
        float c = fc[s * 32 + i], sn = fs[s * 32 + i];
        float ye = e * c - o * sn;
        float yo = e * sn + o * c;
        e = ye; o = yo;
    }
    unsigned int out = f2bf(e) | (f2bf(o) << 16);
    *(unsigned int*)(qr + ((b_ * HH + h) * SS + s) * (long)QKD + 2 * p) = out;
}

// ---------------- RMSNorm(kv_c) + RoPE(k_pe), one block per (b,s) row ----------------
__global__ void __launch_bounds__(256)
rms_rope_kv(const bfu* __restrict__ kv1, const float* __restrict__ wn,
            bfu* __restrict__ kvc, bfu* __restrict__ kpe,
            const float* __restrict__ fc, const float* __restrict__ fs) {
    const int row = blockIdx.x;            // b*S + s
    const int t   = threadIdx.x;
    const int s   = row & (SS - 1);
    const long base = (long)row * NPAD;
    unsigned int v = *(const unsigned int*)(kv1 + base + 2 * t);
    float a = bf2f(v & 0xffff), c2 = bf2f(v >> 16);
    float ssum = a * a + c2 * c2;
#pragma unroll
    for (int d = 1; d < 64; d <<= 1) ssum += __shfl_xor(ssum, d);
    __shared__ float red[4];
    const int lane = t & 63, w = t >> 6;
    if (lane == 0) red[w] = ssum;
    __syncthreads();
    float tot = red[0] + red[1] + red[2] + red[3];
    float scale = rsqrtf(tot * (1.0f / 512.0f) + 1e-6f);
    float w0 = wn[2 * t], w1 = wn[2 * t + 1];
    unsigned int out = f2bf(a * scale * w0) | (f2bf(c2 * scale * w1) << 16);
    *(unsigned int*)(kvc + (long)row * KVR + 2 * t) = out;
    if (t < 32) {
        unsigned int pv = *(const unsigned int*)(kv1 + base + KVR + 2 * t);
        float e = bf2f(pv & 0xffff), o = bf2f(pv >> 16);
        float cc = fc[s * 32 + t], sn = fs[s * 32 + t];
        unsigned int po = f2bf(e * cc - o * sn) | (f2bf(e * sn + o * cc) << 16);
        *(unsigned int*)(kpe + (long)row * ROPE + 2 * t) = po;
    }
}

// ---------------- K assembly: kall[b][h][s][192] = [k_nope | k_pe] ----------------
__global__ void repack_k(const bfu* __restrict__ kvb2, const bfu* __restrict__ kpe,
                         bfu* __restrict__ kall) {
    long t = (long)blockIdx.x * 256 + threadIdx.x;  // one 8-elem chunk
    const long total = (long)BB * HH * SS * 24;
    if (t >= total) return;
    int  ch = (int)(t % 24);
    long r  = t / 24;
    int  s  = (int)(r % SS);
    long r2 = r / SS;
    int  h  = (int)(r2 % HH);
    long b_ = r2 / HH;
    bf16x8 val;
    if (ch < 16)
        val = *(const bf16x8*)(kvb2 + (b_ * SS + s) * 4096 + h * 256 + ch * 8);
    else
        val = *(const bf16x8*)(kpe + (b_ * SS + s) * (long)ROPE + (ch - 16) * 8);
    *(bf16x8*)(kall + ((b_ * HH + h) * SS + s) * (long)QKD + ch * 8) = val;
}

// ---------------- V transpose: vt[b][h][v][s] ----------------
__global__ void transpose_v(const bfu* __restrict__ kvb2, bfu* __restrict__ vt) {
    long t = (long)blockIdx.x * 256 + threadIdx.x;  // one 8-s chunk of one v row
    int  sg = (int)(t & 255);
    long r  = t >> 8;
    int  v  = (int)(r & 127);
    long r2 = r >> 7;
    int  h  = (int)(r2 & 15);
    long b_ = r2 >> 4;
    const long s0 = (long)sg * 8;
    bfu tmp[8];
#pragma unroll
    for (int k = 0; k < 8; ++k)
        tmp[k] = kvb2[(b_ * SS + s0 + k) * 4096 + h * 256 + 128 + v];
    *(bf16x8*)(vt + ((b_ * HH + h) * (long)VD + v) * SS + s0) = *(bf16x8*)tmp;
}

// ---------------- flash causal attention ----------------
// block = (b,h,q-tile of 64); 4 waves x 16 q-rows; KV tile 32
__global__ void __launch_bounds__(256)
attn(const bfu* __restrict__ qr, const bfu* __restrict__ kall,
     const bfu* __restrict__ vt, bfu* __restrict__ ao, float scl2) {
    __shared__ __align__(16) bfu plds[4][16][32];
    const int tid  = threadIdx.x;
    const int lane = tid & 63;
    const int w    = tid >> 6;
    const int bid  = blockIdx.x;
    const int qb   = bid & 31;
    const int h    = (bid >> 5) & 15;
    const int b    = bid >> 9;
    const long bh  = (long)b * HH + h;
    const char* Q  = (const char*)(qr + bh * SS * QKD);
    const char* Kp = (const char*)(kall + bh * SS * QKD);
    const char* Vp = (const char*)(vt + bh * (long)VD * SS);

    const int ql = lane & 15;
    const int kg = lane >> 4;
    const int qrow = qb * 64 + w * 16 + ql;

    bf16x8 qf[6];
#pragma unroll
    for (int d = 0; d < 6; ++d)
        qf[d] = *(const bf16x8*)(Q + (long)qrow * 384 + d * 64 + kg * 16);

    f32x4 accv[8] = {};
    float mreg[4] = {-1e30f, -1e30f, -1e30f, -1e30f};
    float lreg[4] = {0.f, 0.f, 0.f, 0.f};
    const int qg_base = qb * 64 + w * 16 + kg * 4;
    const int kv_end  = qb * 64 + 64;

    for (int kv0 = 0; kv0 < kv_end; kv0 += 32) {
        f32x4 sc0 = {0.f, 0.f, 0.f, 0.f}, sc1 = {0.f, 0.f, 0.f, 0.f};
#pragma unroll
        for (int d = 0; d < 6; ++d) {
            bf16x8 kf = *(const bf16x8*)(Kp + (long)(kv0 + ql) * 384 + d * 64 + kg * 16);
            sc0 = __builtin_amdgcn_mfma_f32_16x16x32_bf16(qf[d], kf, sc0, 0, 0, 0);
        }
#pragma unroll
        for (int d = 0; d < 6; ++d) {
            bf16x8 kf = *(const bf16x8*)(Kp + (long)(kv0 + 16 + ql) * 384 + d * 64 + kg * 16);
            sc1 = __builtin_amdgcn_mfma_f32_16x16x32_bf16(qf[d], kf, sc1, 0, 0, 0);
        }
#pragma unroll
        for (int r = 0; r < 4; ++r) {
            const int qg = qg_base + r;
            float s0 = sc0[r] * scl2;
            float s1 = sc1[r] * scl2;
            const int kc = kv0 + ql;
            if (kc > qg)      s0 = -1e30f;
            if (kc + 16 > qg) s1 = -1e30f;
            float mx = fmaxf(s0, s1);
#pragma unroll
            for (int d = 1; d < 16; d <<= 1) mx = fmaxf(mx, __shfl_xor(mx, d));
            float mn = fmaxf(mreg[r], mx);
            float p0 = exp2f(s0 - mn);
            float p1 = exp2f(s1 - mn);
            float rs = p0 + p1;
#pragma unroll
            for (int d = 1; d < 16; d <<= 1) rs += __shfl_xor(rs, d);
            float al = exp2f(mreg[r] - mn);
            mreg[r] = mn;
            lreg[r] = lreg[r] * al + rs;
#pragma unroll
            for (int v = 0; v < 8; ++v) accv[v][r] *= al;
            const int qlc = kg * 4 + r;
            plds[w][qlc][ql]      = (bfu)f2bf(p0);
            plds[w][qlc][16 + ql] = (bfu)f2bf(p1);
        }
        asm volatile("s_waitcnt lgkmcnt(0)" ::: "memory");
        bf16x8 pa = *(const bf16x8*)(&plds[w][ql][kg * 8]);
#pragma unroll
        for (int v = 0; v < 8; ++v) {
            bf16x8 vf = *(const bf16x8*)(Vp + (long)(v * 16 + ql) * (SS * 2) + (kv0 + kg * 8) * 2);
            accv[v] = __builtin_amdgcn_mfma_f32_16x16x32_bf16(pa, vf, accv[v], 0, 0, 0);
        }
    }
#pragma unroll
    for (int v = 0; v < 8; ++v)
#pragma unroll
        for (int r = 0; r < 4; ++r) {
            float o = accv[v][r] / lreg[r];
            long row = (long)b * SS + qb * 64 + w * 16 + kg * 4 + r;
            ao[row * (long)(HH * VD) + h * VD + v * 16 + ql] = (bfu)f2bf(o);
        }
}

// ---------------- workspace layout (bytes) ----------------
#define O_XB   0L                     // x bf16 33,554,432      (later: vt alias)
#define O_WQ   33554432L              // wq bf16 12,582,912
#define O_WA   46137344L              // wkv_a padded 2,621,440
#define O_WB   48758784L              // wkv_b 4,194,304
#define O_WO   52953088L              // wo 8,388,608
#define O_Q1   61341696L              // q proj out 50,331,648  (later: kall alias)
#define O_KV1  111673344L             // kv_a out 10,485,760
#define O_QR   122159104L             // rope'd q 50,331,648
#define O_KVC  172490752L             // kv_c 8,388,608
#define O_KPE  180879360L             // k_pe 1,048,576
#define O_AO   181927936L             // attn out 33,554,432
#define WS_NEED 215482368L
// kvb2 (8192x4096 bf16 = 67,108,864 B) lives in d_out (16,777,216 fp32 = same size)

extern "C" void kernel_launch(void* const* d_in, const int* in_sizes, int n_in,
                              void* d_out, int out_size, void* d_ws, size_t ws_size,
                              hipStream_t stream) {
    const float* x      = (const float*)d_in[0];
    const float* wq     = (const float*)d_in[1];
    const float* wkv_a  = (const float*)d_in[2];
    const float* kvnw   = (const float*)d_in[3];
    const float* wkv_b  = (const float*)d_in[4];
    const float* wo     = (const float*)d_in[5];
    const float* fcos   = (const float*)d_in[6];
    const float* fsin   = (const float*)d_in[7];
    if (ws_size < (size_t)WS_NEED) return;

    char* ws = (char*)d_ws;
    bfu* xb   = (bfu*)(ws + O_XB);
    bfu* wqb  = (bfu*)(ws + O_WQ);
    bfu* wab  = (bfu*)(ws + O_WA);
    bfu* wbb  = (bfu*)(ws + O_WB);
    bfu* wob  = (bfu*)(ws + O_WO);
    bfu* q1   = (bfu*)(ws + O_Q1);
    bfu* kv1  = (bfu*)(ws + O_KV1);
    bfu* qr   = (bfu*)(ws + O_QR);
    bfu* kvc  = (bfu*)(ws + O_KVC);
    bfu* kpe  = (bfu*)(ws + O_KPE);
    bfu* ao   = (bfu*)(ws + O_AO);
    bfu* kall = q1;                   // alias (q1 dead after rope_q)
    bfu* vt   = xb;                   // alias (xb dead after kv_a GEMM)
    bfu* kvb2 = (bfu*)d_out;          // alias (overwritten by final GEMM)

    const float scl2 = 1.4426950408889634f / sqrtf((float)QKD);

    // 1. casts
    cast_f32_bf16<<<16384, 256, 0, stream>>>(x, xb, 16777216L, 16777216L);
    cast_f32_bf16<<<6144, 256, 0, stream>>>(wq, wqb, 6291456L, 6291456L);
    cast_f32_bf16<<<1280, 256, 0, stream>>>(wkv_a, wab, 1179648L, 1310720L);  // zero-pad rows 576..639
    cast_f32_bf16<<<2048, 256, 0, stream>>>(wkv_b, wbb, 2097152L, 2097152L);
    cast_f32_bf16<<<4096, 256, 0, stream>>>(wo, wob, 4194304L, 4194304L);

    // 2. projections
    gemm_bt<0><<<dim3(24, 64), 256, 0, stream>>>(xb, wqb, q1, HH * QKD, DD);   // q
    gemm_bt<0><<<dim3(5, 64), 256, 0, stream>>>(xb, wab, kv1, NPAD, DD);       // kv_a

    // 3. rope / rmsnorm
    rope_q<<<49152, 256, 0, stream>>>(q1, qr, fcos, fsin);
    rms_rope_kv<<<ROWS, 256, 0, stream>>>(kv1, kvnw, kvc, kpe, fcos, fsin);

    // 4. kv_b projection (into d_out scratch)
    gemm_bt<0><<<dim3(32, 64), 256, 0, stream>>>(kvc, wbb, kvb2, HH * 256, KVR);

    // 5. K assembly + V transpose
    repack_k<<<12288, 256, 0, stream>>>(kvb2, kpe, kall);
    transpose_v<<<8192, 256, 0, stream>>>(kvb2, vt);

    // 6. attention
    attn<<<BB * HH * (SS / 64), 256, 0, stream>>>(qr, kall, vt, ao, scl2);

    // 7. output projection (fp32 out)
    gemm_bt<1><<<dim3(16, 64), 256, 0, stream>>>(ao, wob, d_out, DD, HH * VD);
}

// Round 2
// 634.573 us; speedup vs baseline: 2.6593x; 2.6593x over previous
//
#include <hip/hip_runtime.h>
#include <math.h>

// ---------------- problem constants ----------------
#define BB 4
#define SS 2048
#define DD 2048
#define HH 16
#define NOPE 128
#define ROPE 64
#define VD 128
#define QKD 192         // NOPE+ROPE
#define KVR 512
#define NPAD 640        // KVR+ROPE padded to 128 multiple
#define ROWS (BB*SS)    // 8192

typedef __attribute__((ext_vector_type(8))) short bf16x8;
typedef __attribute__((ext_vector_type(4))) float f32x4;
typedef unsigned short bfu;
typedef __attribute__((address_space(1))) const void GV;
typedef __attribute__((address_space(3))) void LV;

__device__ __forceinline__ float bf2f(unsigned int u) {
    unsigned int i = u << 16; float f; __builtin_memcpy(&f, &i, 4); return f;
}
__device__ __forceinline__ unsigned int f2bf(float f) {
    unsigned int i; __builtin_memcpy(&i, &f, 4);
    return (i + 0x7fffu + ((i >> 16) & 1u)) >> 16;
}

// ---------------- cast fp32 -> bf16 (with optional zero pad) ----------------
__global__ void cast_f32_bf16(const float* __restrict__ src, bfu* __restrict__ dst,
                              long n_src, long n_dst) {
    long i = (long)blockIdx.x * blockDim.x + threadIdx.x;   // one float4 each
    if (i * 4 >= n_dst) return;
    unsigned int lo = 0, hi = 0;
    if (i * 4 < n_src) {
        float4 v = ((const float4*)src)[i];
        lo = f2bf(v.x) | (f2bf(v.y) << 16);
        hi = f2bf(v.z) | (f2bf(v.w) << 16);
    }
    ((uint2*)dst)[i] = make_uint2(lo, hi);
}

// ---------------- 128x128 tile bf16 GEMM, C = A[M,K] @ Bt[N,K]^T ----------------
template <int OUTF32>
__global__ void __launch_bounds__(256)
gemm_bt(const bfu* __restrict__ A, const bfu* __restrict__ Bt,
        void* __restrict__ Cv, int N, int K) {
    __shared__ __align__(16) char lds[32768];
    char* AsB = lds;
    char* BsB = lds + 16384;
    const int tid  = threadIdx.x;
    const int lane = tid & 63;
    const int wid  = tid >> 6;
    const int wr   = wid >> 1, wc = wid & 1;
    const long m0 = (long)blockIdx.y * 128;
    const long n0 = (long)blockIdx.x * 128;

    f32x4 acc[4][4] = {};

    const int lr = lane >> 3;            // row within 8-row stripe
    const int SB = (lane & 7) << 4;      // 16B slot within 128B row

    for (int k0 = 0; k0 < K; k0 += 64) {
        __syncthreads();
#pragma unroll
        for (int i = 0; i < 4; ++i) {
            int rb = wid * 32 + i * 8;   // wave-uniform row base
            int R  = rb + lr;
            int c  = (SB ^ ((R & 7) << 4)) >> 1;   // pre-swizzled source column
            const bfu* gA = A  + (m0 + R) * (long)K + k0 + c;
            const bfu* gB = Bt + (n0 + R) * (long)K + k0 + c;
            __builtin_amdgcn_global_load_lds((GV*)gA, (LV*)(AsB + rb * 128), 16, 0, 0);
            __builtin_amdgcn_global_load_lds((GV*)gB, (LV*)(BsB + rb * 128), 16, 0, 0);
        }
        __syncthreads();
#pragma unroll
        for (int kk = 0; kk < 2; ++kk) {
            bf16x8 av[4], bv[4];
            const int cb = kk * 64 + ((lane >> 4) << 4);
#pragma unroll
            for (int m = 0; m < 4; ++m) {
                int R = wr * 64 + m * 16 + (lane & 15);
                av[m] = *(const bf16x8*)(AsB + R * 128 + (cb ^ ((R & 7) << 4)));
            }
#pragma unroll
            for (int n = 0; n < 4; ++n) {
                int R = wc * 64 + n * 16 + (lane & 15);
                bv[n] = *(const bf16x8*)(BsB + R * 128 + (cb ^ ((R & 7) << 4)));
            }
#pragma unroll
            for (int m = 0; m < 4; ++m)
#pragma unroll
                for (int n = 0; n < 4; ++n)
                    acc[m][n] = __builtin_amdgcn_mfma_f32_16x16x32_bf16(av[m], bv[n], acc[m][n], 0, 0, 0);
        }
    }

    const int cr = (lane >> 4) << 2;
    const int cc = lane & 15;
#pragma unroll
    for (int m = 0; m < 4; ++m)
#pragma unroll
        for (int n = 0; n < 4; ++n)
#pragma unroll
            for (int r = 0; r < 4; ++r) {
                long row = m0 + wr * 64 + m * 16 + cr + r;
                long col = n0 + wc * 64 + n * 16 + cc;
                if (OUTF32) ((float*)Cv)[row * N + col] = acc[m][n][r];
                else        ((bfu*)Cv)[row * N + col] = (bfu)f2bf(acc[m][n][r]);
            }
}

// ---------------- RoPE on q_pe + rearrange q -> [b][h][s][192] ----------------
__global__ void rope_q(const bfu* __restrict__ q1, bfu* __restrict__ qr,
                       const float* __restrict__ fc, const float* __restrict__ fs) {
    long t = (long)blockIdx.x * 256 + threadIdx.x;   // one (e,o) pair
    const long total = (long)BB * HH * SS * 96;
    if (t >= total) return;
    int  p  = (int)(t % 96);
    long r  = t / 96;
    int  h  = (int)(r % HH);
    long bs = r / HH;                 // b*S + s
    int  s  = (int)(bs % SS);
    long b_ = bs / SS;
    unsigned int v = *(const unsigned int*)(q1 + bs * (HH * QKD) + h * QKD + 2 * p);
    float e = bf2f(v & 0xffff), o = bf2f(v >> 16);
    if (p >= 64) {
        int i = p - 64;
        float c = fc[s * 32 + i], sn = fs[s * 32 + i];
        float ye = e * c - o * sn;
        float yo = e * sn + o * c;
        e = ye; o = yo;
    }
    unsigned int out = f2bf(e) | (f2bf(o) << 16);
    *(unsigned int*)(qr + ((b_ * HH + h) * SS + s) * (long)QKD + 2 * p) = out;
}

// ---------------- RMSNorm(kv_c) + RoPE(k_pe), one block per (b,s) row ----------------
__global__ void __launch_bounds__(256)
rms_rope_kv(const bfu* __restrict__ kv1, const float* __restrict__ wn,
            bfu* __restrict__ kvc, bfu* __restrict__ kpe,
            const float* __restrict__ fc, const float* __restrict__ fs) {
    const int row = blockIdx.x;            // b*S + s
    const int t   = threadIdx.x;
    const int s   = row & (SS - 1);
    const long base = (long)row * NPAD;
    unsigned int v = *(const unsigned int*)(kv1 + base + 2 * t);
    float a = bf2f(v & 0xffff), c2 = bf2f(v >> 16);
    float ssum = a * a + c2 * c2;
#pragma unroll
    for (int d = 1; d < 64; d <<= 1) ssum += __shfl_xor(ssum, d);
    __shared__ float red[4];
    const int lane = t & 63, w = t >> 6;
    if (lane == 0) red[w] = ssum;
    __syncthreads();
    float tot = red[0] + red[1] + red[2] + red[3];
    float scale = rsqrtf(tot * (1.0f / 512.0f) + 1e-6f);
    float w0 = wn[2 * t], w1 = wn[2 * t + 1];
    unsigned int out = f2bf(a * scale * w0) | (f2bf(c2 * scale * w1) << 16);
    *(unsigned int*)(kvc + (long)row * KVR + 2 * t) = out;
    if (t < 32) {
        unsigned int pv = *(const unsigned int*)(kv1 + base + KVR + 2 * t);
        float e = bf2f(pv & 0xffff), o = bf2f(pv >> 16);
        float cc = fc[s * 32 + t], sn = fs[s * 32 + t];
        unsigned int po = f2bf(e * cc - o * sn) | (f2bf(e * sn + o * cc) << 16);
        *(unsigned int*)(kpe + (long)row * ROPE + 2 * t) = po;
    }
}

// ---------------- K assembly: kall[b][h][s][192] = [k_nope | k_pe] ----------------
__global__ void repack_k(const bfu* __restrict__ kvb2, const bfu* __restrict__ kpe,
                         bfu* __restrict__ kall) {
    long t = (long)blockIdx.x * 256 + threadIdx.x;  // one 8-elem chunk
    const long total = (long)BB * HH * SS * 24;
    if (t >= total) return;
    int  ch = (int)(t % 24);
    long r  = t / 24;
    int  s  = (int)(r % SS);
    long r2 = r / SS;
    int  h  = (int)(r2 % HH);
    long b_ = r2 / HH;
    bf16x8 val;
    if (ch < 16)
        val = *(const bf16x8*)(kvb2 + (b_ * SS + s) * 4096 + h * 256 + ch * 8);
    else
        val = *(const bf16x8*)(kpe + (b_ * SS + s) * (long)ROPE + (ch - 16) * 8);
    *(bf16x8*)(kall + ((b_ * HH + h) * SS + s) * (long)QKD + ch * 8) = val;
}

// ---------------- V transpose via LDS tile: vt[b][h][v][s] ----------------
// block = (bh, s-tile of 64). Stage [64 s][128 v] with chunk^=(row>>3)&7 swizzle,
// read columns, write coalesced bf16x8 rows of vt.
__global__ void __launch_bounds__(256)
transpose_v2(const bfu* __restrict__ kvb2, bfu* __restrict__ vt) {
    __shared__ __align__(16) char tile[64 * 256];   // 16 KB
    const int tid = threadIdx.x;
    const int bid = blockIdx.x;          // 64 bh * 32 s-tiles
    const int st  = bid & 31;
    const int bh  = bid >> 5;
    const int h   = bh & 15;
    const long b_ = bh >> 4;
    const long sbase = b_ * SS + st * 64;
    // stage: 64 rows x 16 chunks(16B) ; source chunk pre-swizzled
#pragma unroll
    for (int i = 0; i < 4; ++i) {
        int idx = i * 256 + tid;
        int row = idx >> 4;
        int ch  = (idx & 15) ^ ((row >> 3) & 7);
        const bfu* src = kvb2 + (sbase + row) * 4096 + h * 256 + 128 + ch * 8;
        __builtin_amdgcn_global_load_lds((GV*)src, (LV*)(tile + idx * 16), 16, 0, 0);
    }
    __syncthreads();
#pragma unroll
    for (int i = 0; i < 4; ++i) {
        int idx = i * 256 + tid;
        int sc = idx & 7;            // s-chunk of 8
        int v  = (idx >> 3) & 127;
        bfu tmp[8];
#pragma unroll
        for (int k = 0; k < 8; ++k) {
            int row = sc * 8 + k;
            tmp[k] = *(const bfu*)(tile + row * 256 + (((v >> 3) ^ ((row >> 3) & 7)) << 4) + (v & 7) * 2);
        }
        *(bf16x8*)(vt + ((long)bh * VD + v) * SS + st * 64 + sc * 8) = *(bf16x8*)tmp;
    }
}

// ---------------- flash causal attention v2 ----------------
// block = (bh, q-tile of 128); 4 waves x 32 q-rows; KV tile 64, LDS-staged.
// scores computed transposed: C[kv][q] = mfma(K_frag, Q_frag) -> kv-reduce is
// in-register + 2 shuffles. P repacked through per-wave swizzled LDS tile.
__global__ void __launch_bounds__(256)
attn(const bfu* __restrict__ qr, const bfu* __restrict__ kall,
     const bfu* __restrict__ vt, bfu* __restrict__ ao, float scl2) {
    __shared__ __align__(16) char kbuf[64 * 384];    // 24576
    __shared__ __align__(16) char vbuf[128 * 128];   // 16384
    __shared__ __align__(16) char pbuf[4][2048];     //  8192
    const int tid  = threadIdx.x;
    const int lane = tid & 63;
    const int w    = tid >> 6;
    const int ql   = lane & 15;
    const int kg   = lane >> 4;
    const int bid  = blockIdx.x;
    const int qb   = 15 - (bid >> 6);    // longest blocks first
    const int bh   = bid & 63;
    const int h    = bh & 15;
    const int b    = bh >> 4;
    const char* Q  = (const char*)(qr + (long)bh * SS * QKD);
    const char* Kp = (const char*)(kall + (long)bh * SS * QKD);
    const char* Vp = (const char*)(vt + (long)bh * VD * SS);
    char* pw = pbuf[w];

    // Q fragments: rows qb*128 + w*32 + m*16 + ql ; B-operand layout
    bf16x8 qf[2][6];
#pragma unroll
    for (int m = 0; m < 2; ++m)
#pragma unroll
        for (int d = 0; d < 6; ++d)
            qf[m][d] = *(const bf16x8*)(Q + (long)(qb * 128 + w * 32 + m * 16 + ql) * 384 + d * 64 + kg * 16);

    f32x4 accv[2][8] = {};
    float ms[2] = {-1e30f, -1e30f};
    float ls[2] = {0.f, 0.f};
    const int kv_end = qb * 128 + 128;

    for (int kv0 = 0; kv0 < kv_end; kv0 += 64) {
        __syncthreads();                 // all waves done reading K/V LDS
        // stage K tile [64][192] (6 x 256 chunks of 16B), source pre-swizzled
#pragma unroll
        for (int i = 0; i < 6; ++i) {
            int idx  = i * 256 + tid;
            int row  = idx / 24;
            int slot = idx - row * 24;
            int ss   = slot ^ (row & 7);
            const char* src = Kp + (long)(kv0 + row) * 384 + ss * 16;
            __builtin_amdgcn_global_load_lds((GV*)src, (LV*)(kbuf + idx * 16), 16, 0, 0);
        }
        // stage V^T tile [128][64] (4 x 256 chunks)
#pragma unroll
        for (int i = 0; i < 4; ++i) {
            int idx  = i * 256 + tid;
            int row  = idx >> 3;
            int slot = idx & 7;
            int ss   = slot ^ (row & 7);
            const char* src = Vp + (long)row * (SS * 2) + kv0 * 2 + ss * 16;
            __builtin_amdgcn_global_load_lds((GV*)src, (LV*)(vbuf + idx * 16), 16, 0, 0);
        }
        __syncthreads();                 // staged data visible

#pragma unroll
        for (int m = 0; m < 2; ++m) {
            // ---- scores: C[kv][q] ----
            f32x4 sc[4] = {};
#pragma unroll
            for (int j = 0; j < 4; ++j)
#pragma unroll
                for (int d = 0; d < 6; ++d) {
                    int row  = j * 16 + ql;
                    int slot = (d * 4 + kg) ^ (ql & 7);
                    bf16x8 kf = *(const bf16x8*)(kbuf + row * 384 + slot * 16);
                    sc[j] = __builtin_amdgcn_mfma_f32_16x16x32_bf16(kf, qf[m][d], sc[j], 0, 0, 0);
                }
            // ---- mask + online softmax (q = ql lane-local column) ----
            const int qa = qb * 128 + w * 32 + m * 16 + ql;
            float p[4][4];
            float mx = -1e30f;
#pragma unroll
            for (int j = 0; j < 4; ++j)
#pragma unroll
                for (int r = 0; r < 4; ++r) {
                    float s = sc[j][r] * scl2;
                    int kv = kv0 + j * 16 + kg * 4 + r;
                    s = (kv > qa) ? -1e30f : s;
                    p[j][r] = s;
                    mx = fmaxf(mx, s);
                }
            mx = fmaxf(mx, __shfl_xor(mx, 16));
            mx = fmaxf(mx, __shfl_xor(mx, 32));
            float mn = fmaxf(ms[m], mx);
            float al = exp2f(ms[m] - mn);
            ms[m] = mn;
            float rs = 0.f;
#pragma unroll
            for (int j = 0; j < 4; ++j)
#pragma unroll
                for (int r = 0; r < 4; ++r) {
                    float e = exp2f(p[j][r] - mn);
                    p[j][r] = e;
                    rs += e;
                }
            rs += __shfl_xor(rs, 16);
            rs += __shfl_xor(rs, 32);
            ls[m] = ls[m] * al + rs;
            // transpose rescale factor to accv row basis (q = kg*4+r)
            float alT[4];
#pragma unroll
            for (int r = 0; r < 4; ++r)
                alT[r] = __shfl(al, (lane & 48) + kg * 4 + r);
#pragma unroll
            for (int v8 = 0; v8 < 8; ++v8)
#pragma unroll
                for (int r = 0; r < 4; ++r)
                    accv[m][v8][r] *= alT[r];
            // ---- repack P -> per-wave LDS [16 q][64 kv], swizzled ----
#pragma unroll
            for (int j = 0; j < 4; ++j) {
                uint2 u;
                u.x = f2bf(p[j][0]) | (f2bf(p[j][1]) << 16);
                u.y = f2bf(p[j][2]) | (f2bf(p[j][3]) << 16);
                int slot = (2 * j + (kg >> 1)) ^ (ql & 7);
                *(uint2*)(pw + ql * 128 + slot * 16 + (kg & 1) * 8) = u;
            }
            asm volatile("s_waitcnt lgkmcnt(0)" ::: "memory");
            // ---- PV: out[q][v] += P V ----
#pragma unroll
            for (int t = 0; t < 2; ++t) {
                int ps = (t * 4 + kg) ^ (ql & 7);
                bf16x8 pa = *(const bf16x8*)(pw + ql * 128 + ps * 16);
#pragma unroll
                for (int v8 = 0; v8 < 8; ++v8) {
                    int vrow = v8 * 16 + ql;
                    int vs   = (t * 4 + kg) ^ (ql & 7);
                    bf16x8 vf = *(const bf16x8*)(vbuf + vrow * 128 + vs * 16);
                    accv[m][v8] = __builtin_amdgcn_mfma_f32_16x16x32_bf16(pa, vf, accv[m][v8], 0, 0, 0);
                }
            }
        }
    }
    // ---- epilogue ----
#pragma unroll
    for (int m = 0; m < 2; ++m) {
        float lT[4];
#pragma unroll
        for (int r = 0; r < 4; ++r)
            lT[r] = __shfl(ls[m], (lane & 48) + kg * 4 + r);
#pragma unroll
        for (int v8 = 0; v8 < 8; ++v8)
#pragma unroll
            for (int r = 0; r < 4; ++r) {
                float o = accv[m][v8][r] / lT[r];
                long row = (long)b * SS + qb * 128 + w * 32 + m * 16 + kg * 4 + r;
                ao[row * (long)(HH * VD) + h * VD + v8 * 16 + ql] = (bfu)f2bf(o);
            }
    }
}

// ---------------- workspace layout (bytes) ----------------
#define O_XB   0L                     // x bf16 33,554,432      (later: vt alias)
#define O_WQ   33554432L              // wq bf16 12,582,912
#define O_WA   46137344L              // wkv_a padded 2,621,440
#define O_WB   48758784L              // wkv_b 4,194,304
#define O_WO   52953088L              // wo 8,388,608
#define O_Q1   61341696L              // q proj out 50,331,648  (later: kall alias)
#define O_KV1  111673344L             // kv_a out 10,485,760
#define O_QR   122159104L             // rope'd q 50,331,648
#define O_KVC  172490752L             // kv_c 8,388,608
#define O_KPE  180879360L             // k_pe 1,048,576
#define O_AO   181927936L             // attn out 33,554,432
#define WS_NEED 215482368L
// kvb2 (8192x4096 bf16 = 67,108,864 B) lives in d_out (16,777,216 fp32 = same size)

extern "C" void kernel_launch(void* const* d_in, const int* in_sizes, int n_in,
                              void* d_out, int out_size, void* d_ws, size_t ws_size,
                              hipStream_t stream) {
    const float* x      = (const float*)d_in[0];
    const float* wq     = (const float*)d_in[1];
    const float* wkv_a  = (const float*)d_in[2];
    const float* kvnw   = (const float*)d_in[3];
    const float* wkv_b  = (const float*)d_in[4];
    const float* wo     = (const float*)d_in[5];
    const float* fcos   = (const float*)d_in[6];
    const float* fsin   = (const float*)d_in[7];
    if (ws_size < (size_t)WS_NEED) return;

    char* ws = (char*)d_ws;
    bfu* xb   = (bfu*)(ws + O_XB);
    bfu* wqb  = (bfu*)(ws + O_WQ);
    bfu* wab  = (bfu*)(ws + O_WA);
    bfu* wbb  = (bfu*)(ws + O_WB);
    bfu* wob  = (bfu*)(ws + O_WO);
    bfu* q1   = (bfu*)(ws + O_Q1);
    bfu* kv1  = (bfu*)(ws + O_KV1);
    bfu* qr   = (bfu*)(ws + O_QR);
    bfu* kvc  = (bfu*)(ws + O_KVC);
    bfu* kpe  = (bfu*)(ws + O_KPE);
    bfu* ao   = (bfu*)(ws + O_AO);
    bfu* kall = q1;                   // alias (q1 dead after rope_q)
    bfu* vt   = xb;                   // alias (xb dead after kv_a GEMM)
    bfu* kvb2 = (bfu*)d_out;          // alias (overwritten by final GEMM)

    const float scl2 = 1.4426950408889634f / sqrtf((float)QKD);

    // 1. casts
    cast_f32_bf16<<<16384, 256, 0, stream>>>(x, xb, 16777216L, 16777216L);
    cast_f32_bf16<<<6144, 256, 0, stream>>>(wq, wqb, 6291456L, 6291456L);
    cast_f32_bf16<<<1280, 256, 0, stream>>>(wkv_a, wab, 1179648L, 1310720L);  // zero-pad rows 576..639
    cast_f32_bf16<<<2048, 256, 0, stream>>>(wkv_b, wbb, 2097152L, 2097152L);
    cast_f32_bf16<<<4096, 256, 0, stream>>>(wo, wob, 4194304L, 4194304L);

    // 2. projections
    gemm_bt<0><<<dim3(24, 64), 256, 0, stream>>>(xb, wqb, q1, HH * QKD, DD);   // q
    gemm_bt<0><<<dim3(5, 64), 256, 0, stream>>>(xb, wab, kv1, NPAD, DD);       // kv_a

    // 3. rope / rmsnorm
    rope_q<<<49152, 256, 0, stream>>>(q1, qr, fcos, fsin);
    rms_rope_kv<<<ROWS, 256, 0, stream>>>(kv1, kvnw, kvc, kpe, fcos, fsin);

    // 4. kv_b projection (into d_out scratch)
    gemm_bt<0><<<dim3(32, 64), 256, 0, stream>>>(kvc, wbb, kvb2, HH * 256, KVR);

    // 5. K assembly + V transpose
    repack_k<<<12288, 256, 0, stream>>>(kvb2, kpe, kall);
    transpose_v2<<<2048, 256, 0, stream>>>(kvb2, vt);

    // 6. attention (1024 blocks: 64 bh x 16 q-tiles of 128, longest first)
    attn<<<1024, 256, 0, stream>>>(qr, kall, vt, ao, scl2);

    // 7. output projection (fp32 out)
    gemm_bt<1><<<dim3(16, 64), 256, 0, stream>>>(ao, wob, d_out, DD, HH * VD);
}